// Round 6
// baseline (426.087 us; speedup 1.0000x reference)
//
#include <hip/hip_runtime.h>

// ODE-RNN via MFMA, 16-wave blocks (4 waves/SIMD) for latency hiding.
// 256 blocks x 1024 threads; NT=8 trajs/block; W1 weights in VGPRs as bf16
// B-fragments (<=10 frags/wave), W2 weights in LDS (transposed [64][128] bf16,
// read as B-fragments); activations bf16 in LDS; GRU state fp32 in regs.
// Roles: waves 0-3 (R0): f1/z1/h1 tile wv + f2/z2/h2 tile wv + state+stores.
//        waves 4-7 (R1): f1/z1/h1 tile wv.
//        waves 8-15(R2): r1 tile wv-8; waves 8-11 also r2 tile wv-8 + ch build
//                        + x pipeline (load s+1 ahead in regs).
// Fragment mapping (16x16x32 bf16): A: lane l -> A[l&15][kt*32+(l>>4)*8+j],
// B: lane l -> B[kt*32+(l>>4)*8+j][l&15], C/D: col=l&15, row=(l>>4)*4+reg.

#define NBT   2048
#define TSTEP 200
#define NT    8

typedef short s8v __attribute__((ext_vector_type(8)));   // 8 bf16 (4 VGPRs)
typedef float f4v __attribute__((ext_vector_type(4)));

// pitches: (pitch/4)%32==4 -> row-base bank 4r mod 32 (2-way worst), 16B aligned
#define RB_Y 144    // y  [16][64] bf16 (+pad)
#define RB_C 272    // c/h [16][128] bf16 (+pad)
#define RB_W 272    // W2T [64][128] bf16 (+pad)
#define OFF_Y   0
#define OFF_C   2304
#define OFF_HF  6656
#define OFF_HZ  11008
#define OFF_HR  15360
#define OFF_HH  19712
#define OFF_WF2 24064
#define OFF_WZ2 41472
#define OFF_WR2 58880
#define OFF_WH2 76288
#define SMEM_TOT 93696

__device__ __forceinline__ unsigned cvtpk(float lo, float hi) {
    unsigned r;
    asm("v_cvt_pk_bf16_f32 %0, %1, %2" : "=v"(r) : "v"(lo), "v"(hi));
    return r;
}
__device__ __forceinline__ unsigned short f2bf(float f) {  // staging only
    unsigned int b = __float_as_uint(f);
    return (unsigned short)((b + 0x7fffu + ((b >> 16) & 1u)) >> 16);
}
__device__ __forceinline__ float bf2f(unsigned short u) {
    return __uint_as_float(((unsigned)u) << 16);
}
__device__ __forceinline__ float tanh_f(float x) {
    float e = __expf(2.0f * x);
    return fmaf(-2.0f, __builtin_amdgcn_rcpf(e + 1.0f), 1.0f);
}
__device__ __forceinline__ float sigm_f(float x) {
    return __builtin_amdgcn_rcpf(1.0f + __expf(-x));
}
__device__ __forceinline__ f4v mfma16(s8v a, s8v b, f4v c) {
    return __builtin_amdgcn_mfma_f32_16x16x32_bf16(a, b, c, 0, 0, 0);
}
__device__ __forceinline__ f4v splat(float b) { f4v v = {b, b, b, b}; return v; }

// W1 B-fragment from global: lane holds W[k0+j][n], j=0..7 (zero-padded)
__device__ __forceinline__ s8v load_bfrag(const float* __restrict__ W,
                                          int Ncols, int Krows, int k0, int n) {
    s8v r;
#pragma unroll
    for (int j = 0; j < 8; ++j) {
        const int k = k0 + j;
        const float v = (k < Krows && n < Ncols) ? W[k * Ncols + j == j ? n : n] : 0.0f;
        r[j] = (short)f2bf((k < Krows && n < Ncols) ? W[k * Ncols + n] : 0.0f);
    }
    return r;
}

// fragment read (A from act tiles, B from W2T): lane l -> row (l&15) of base,
// bytes kt*64 + (l>>4)*16
template <int RB>
__device__ __forceinline__ s8v load_af(const char* base, int lane, int kt) {
    return *(const s8v*)(base + (lane & 15) * RB + ((lane >> 4) * 16) + kt * 64);
}

// write 4 fp32 (rows rb..rb+3, one col) as bf16 via cvt_pk
__device__ __forceinline__ void store4(char* base, int col2, int rb, int pitch,
                                       float v0, float v1, float v2, float v3) {
    const unsigned u01 = cvtpk(v0, v1), u23 = cvtpk(v2, v3);
    *(short*)(base + (rb + 0) * pitch + col2) = (short)(u01 & 0xffffu);
    *(short*)(base + (rb + 1) * pitch + col2) = (short)(u01 >> 16);
    *(short*)(base + (rb + 2) * pitch + col2) = (short)(u23 & 0xffffu);
    *(short*)(base + (rb + 3) * pitch + col2) = (short)(u23 >> 16);
}
__device__ __forceinline__ void store_tanh(char* base, int n0, int lane, f4v a) {
    store4(base, (n0 + (lane & 15)) * 2, (lane >> 4) * 4, RB_C,
           tanh_f(a[0]), tanh_f(a[1]), tanh_f(a[2]), tanh_f(a[3]));
}

// stage W2 [100][64] fp32 -> W2T LDS [64 rows][128 k] bf16 (pad pre-zeroed)
__device__ void stage_w2t(const float* __restrict__ W, char* __restrict__ dst,
                          int tid) {
    for (int idx = tid; idx < 6400; idx += 1024) {
        const int k = idx >> 6, n = idx & 63;
        *(unsigned short*)(dst + n * RB_W + k * 2) = f2bf(W[idx]);
    }
}

__global__ __launch_bounds__(1024, 4) void ode_rnn_16w(
    const float* __restrict__ data, const float* __restrict__ tsv,
    const float* __restrict__ Wf1, const float* __restrict__ bf1,
    const float* __restrict__ Wf2, const float* __restrict__ bf2,
    const float* __restrict__ Wz1, const float* __restrict__ bz1,
    const float* __restrict__ Wz2, const float* __restrict__ bz2,
    const float* __restrict__ Wr1, const float* __restrict__ br1,
    const float* __restrict__ Wr2, const float* __restrict__ br2,
    const float* __restrict__ Wh1, const float* __restrict__ bh1,
    const float* __restrict__ Wh2, const float* __restrict__ bh2,
    float* __restrict__ out_yi, float* __restrict__ out_ys)
{
    extern __shared__ __align__(16) char smem[];

    const int tid  = threadIdx.x;
    const int lane = tid & 63;
    const int wv   = tid >> 6;                 // 0..15
    const int role = (wv < 4) ? 0 : (wv < 8) ? 1 : 2;
    const int b0   = blockIdx.x * NT;

    for (int i = tid; i < SMEM_TOT / 4; i += 1024) ((unsigned*)smem)[i] = 0u;
    __syncthreads();
    stage_w2t(Wf2, smem + OFF_WF2, tid);
    stage_w2t(Wz2, smem + OFF_WZ2, tid);
    stage_w2t(Wr2, smem + OFF_WR2, tid);
    stage_w2t(Wh2, smem + OFF_WH2, tid);

    // ---- W1 fragments in VGPRs (max 10 frags/wave) ----
    const int kb  = (lane >> 4) * 8;
    const int wt1 = (role == 2) ? (wv - 8) : wv;       // W1 tile 0..7
    const int n1  = wt1 * 16 + (lane & 15);
    s8v B1[10];
    float b1a = 0.0f, b1z = 0.0f, b1h = 0.0f;
    if (role == 2) {
#pragma unroll
        for (int kt = 0; kt < 4; ++kt)
            B1[kt] = load_bfrag(Wr1, 100, 128, kt * 32 + kb, n1);
        b1a = (n1 < 100) ? br1[n1] : 0.0f;
    } else {
        B1[0] = load_bfrag(Wf1, 100, 64, 0 * 32 + kb, n1);
        B1[1] = load_bfrag(Wf1, 100, 64, 1 * 32 + kb, n1);
#pragma unroll
        for (int kt = 0; kt < 4; ++kt) {
            B1[2 + kt] = load_bfrag(Wz1, 100, 128, kt * 32 + kb, n1);
            B1[6 + kt] = load_bfrag(Wh1, 100, 128, kt * 32 + kb, n1);
        }
        b1a = (n1 < 100) ? bf1[n1] : 0.0f;
        b1z = (n1 < 100) ? bz1[n1] : 0.0f;
        b1h = (n1 < 100) ? bh1[n1] : 0.0f;
    }

    // W2 tile (R0: wv 0-3; waves 8-11: wv-8)
    const int tw2  = wv & 3;
    const int n2   = tw2 * 16 + (lane & 15);
    const int col2 = n2 * 2;
    const int rb   = (lane >> 4) * 4;
    const float bF2 = (role == 0) ? bf2[n2] : 0.0f;
    const float bZ2 = (role == 0) ? bz2[n2] : 0.0f;
    const float bH2 = (role == 0) ? bh2[n2] : 0.0f;
    const bool  xw  = (wv >= 8 && wv < 12);
    const float bR2 = xw ? br2[n2] : 0.0f;

    // x pipeline (waves 8-11): hold x for step s in regs, loaded 1 step ahead
    const int t2  = tid & 255;
    const int xtr = t2 >> 5;
    const int xd  = (t2 & 31) * 2;
    float2 xv = {0.0f, 0.0f};
    if (xw)
        xv = *(const float2*)&data[((size_t)(b0 + xtr) * TSTEP + 1) * 64 + xd];

    f4v y_reg = splat(0.0f), yode = splat(0.0f), zf = splat(0.0f);
    __syncthreads();

    for (int s = 0; s < TSTEP - 1; ++s) {
        const float dt = (s == 0) ? (tsv[1] - tsv[0]) : (tsv[s - 1] - tsv[s]);

        // ---- P1: f1 hidden (waves 0-7) | x write + next-x issue (8-11) ----
        if (role < 2) {
            const s8v ya0 = load_af<RB_Y>(smem + OFF_Y, lane, 0);
            const s8v ya1 = load_af<RB_Y>(smem + OFF_Y, lane, 1);
            f4v a = splat(b1a);
            a = mfma16(ya0, B1[0], a);
            a = mfma16(ya1, B1[1], a);
            store_tanh(smem + OFF_HF, wt1 * 16, lane, a);
        } else if (xw) {
            *(unsigned*)(smem + OFF_C + xtr * RB_C + 128 + (t2 & 31) * 4) =
                cvtpk(xv.x, xv.y);
            const int snx = (s + 2 < TSTEP) ? (s + 2) : (TSTEP - 1);
            xv = *(const float2*)&data[((size_t)(b0 + xtr) * TSTEP + snx) * 64 + xd];
        }
        __syncthreads();

        // ---- P2: f2 out (waves 0-3) -> yode -> c[:, :64] ----
        if (role == 0) {
            f4v ac = splat(bF2);
#pragma unroll
            for (int kt = 0; kt < 4; ++kt)
                ac = mfma16(load_af<RB_C>(smem + OFF_HF, lane, kt),
                            load_af<RB_W>(smem + OFF_WF2 + tw2 * 16 * RB_W, lane, kt), ac);
#pragma unroll
            for (int r = 0; r < 4; ++r) yode[r] = fmaf(dt, ac[r], y_reg[r]);
            store4(smem + OFF_C, col2, rb, RB_C, yode[0], yode[1], yode[2], yode[3]);
        }
        __syncthreads();

        // ---- P3: z1 (waves 0-7) | r1 (waves 8-15) from c ----
        {
            const s8v c0 = load_af<RB_C>(smem + OFF_C, lane, 0);
            const s8v c1 = load_af<RB_C>(smem + OFF_C, lane, 1);
            const s8v c2 = load_af<RB_C>(smem + OFF_C, lane, 2);
            const s8v c3 = load_af<RB_C>(smem + OFF_C, lane, 3);
            if (role == 2) {
                f4v ar = splat(b1a);
                ar = mfma16(c0, B1[0], ar); ar = mfma16(c1, B1[1], ar);
                ar = mfma16(c2, B1[2], ar); ar = mfma16(c3, B1[3], ar);
                store_tanh(smem + OFF_HR, wt1 * 16, lane, ar);
            } else {
                f4v az = splat(b1z);
                az = mfma16(c0, B1[2], az); az = mfma16(c1, B1[3], az);
                az = mfma16(c2, B1[4], az); az = mfma16(c3, B1[5], az);
                store_tanh(smem + OFF_HZ, wt1 * 16, lane, az);
            }
        }
        __syncthreads();

        // ---- P4: z2 (waves 0-3, zf regs) | r2 + ch=yode*r (waves 8-11) ----
        if (role == 0) {
            f4v az = splat(bZ2);
#pragma unroll
            for (int kt = 0; kt < 4; ++kt)
                az = mfma16(load_af<RB_C>(smem + OFF_HZ, lane, kt),
                            load_af<RB_W>(smem + OFF_WZ2 + tw2 * 16 * RB_W, lane, kt), az);
#pragma unroll
            for (int r = 0; r < 4; ++r) zf[r] = sigm_f(az[r]);
        } else if (xw) {
            f4v ar = splat(bR2);
#pragma unroll
            for (int kt = 0; kt < 4; ++kt)
                ar = mfma16(load_af<RB_C>(smem + OFF_HR, lane, kt),
                            load_af<RB_W>(smem + OFF_WR2 + tw2 * 16 * RB_W, lane, kt), ar);
            float ch[4];
#pragma unroll
            for (int r = 0; r < 4; ++r) {
                const unsigned short yv =
                    *(const unsigned short*)(smem + OFF_C + (rb + r) * RB_C + col2);
                ch[r] = bf2f(yv) * sigm_f(ar[r]);
            }
            store4(smem + OFF_C, col2, rb, RB_C, ch[0], ch[1], ch[2], ch[3]);
        }
        __syncthreads();

        // ---- P5: h1 hidden (waves 0-7) from [ch | x] ----
        if (role < 2) {
            const s8v d0 = load_af<RB_C>(smem + OFF_C, lane, 0);
            const s8v d1 = load_af<RB_C>(smem + OFF_C, lane, 1);
            const s8v d2 = load_af<RB_C>(smem + OFF_C, lane, 2);
            const s8v d3 = load_af<RB_C>(smem + OFF_C, lane, 3);
            f4v ah = splat(b1h);
            ah = mfma16(d0, B1[6], ah); ah = mfma16(d1, B1[7], ah);
            ah = mfma16(d2, B1[8], ah); ah = mfma16(d3, B1[9], ah);
            store_tanh(smem + OFF_HH, wt1 * 16, lane, ah);
        }
        __syncthreads();

        // ---- P6: h2 out (waves 0-3); y update; LDS y + global stores ----
        if (role == 0) {
            f4v ah = splat(bH2);
#pragma unroll
            for (int kt = 0; kt < 4; ++kt)
                ah = mfma16(load_af<RB_C>(smem + OFF_HH, lane, kt),
                            load_af<RB_W>(smem + OFF_WH2 + tw2 * 16 * RB_W, lane, kt), ah);
#pragma unroll
            for (int r = 0; r < 4; ++r) {
                const float h = tanh_f(ah[r]);
                y_reg[r] = (1.0f - zf[r]) * h + zf[r] * yode[r];
            }
            store4(smem + OFF_Y, col2, rb, RB_Y, y_reg[0], y_reg[1], y_reg[2], y_reg[3]);
            if (lane < 32) {
#pragma unroll
                for (int r = 0; r < 4; ++r)
                    out_ys[((size_t)(b0 + rb + r) * (TSTEP - 1) + s) * 64 + n2] =
                        y_reg[r];
                if (s == TSTEP - 2) {
#pragma unroll
                    for (int r = 0; r < 4; ++r)
                        out_yi[(size_t)(b0 + rb + r) * 64 + n2] = y_reg[r];
                }
            }
        }
        __syncthreads();
    }
}

extern "C" void kernel_launch(void* const* d_in, const int* in_sizes, int n_in,
                              void* d_out, int out_size, void* d_ws, size_t ws_size,
                              hipStream_t stream) {
    const float* data = (const float*)d_in[0];
    const float* tsv  = (const float*)d_in[1];
    const float* Wf1 = (const float*)d_in[2];  const float* bf1 = (const float*)d_in[3];
    const float* Wf2 = (const float*)d_in[4];  const float* bf2 = (const float*)d_in[5];
    const float* Wz1 = (const float*)d_in[6];  const float* bz1 = (const float*)d_in[7];
    const float* Wz2 = (const float*)d_in[8];  const float* bz2 = (const float*)d_in[9];
    const float* Wr1 = (const float*)d_in[10]; const float* br1 = (const float*)d_in[11];
    const float* Wr2 = (const float*)d_in[12]; const float* br2 = (const float*)d_in[13];
    const float* Wh1 = (const float*)d_in[14]; const float* bh1 = (const float*)d_in[15];
    const float* Wh2 = (const float*)d_in[16]; const float* bh2 = (const float*)d_in[17];

    float* out_yi = (float*)d_out;
    float* out_ys = out_yi + (size_t)NBT * 64;

    (void)hipFuncSetAttribute((const void*)ode_rnn_16w,
                              hipFuncAttributeMaxDynamicSharedMemorySize, SMEM_TOT);

    ode_rnn_16w<<<NBT / NT, 1024, SMEM_TOT, stream>>>(
        data, tsv, Wf1, bf1, Wf2, bf2, Wz1, bz1, Wz2, bz2,
        Wr1, br1, Wr2, br2, Wh1, bh1, Wh2, bh2, out_yi, out_ys);
}